// Round 6
// baseline (120.767 us; speedup 1.0000x reference)
//
#include <hip/hip_runtime.h>

typedef __attribute__((ext_vector_type(8))) short short8;
typedef __attribute__((ext_vector_type(4))) float f32x4;
typedef __attribute__((ext_vector_type(4))) unsigned short us4;

constexpr int NB = 8, NC = 256, IH = 64, IW = 96;
constexpr int PATCH = 21, RAD = 10;
constexpr int TI = 8, TJ = 8;            // pixel tile
constexpr int WIN = 28, NWIN = 784;      // x2 window per tile
constexpr int KC = 32, NKS = NC / KC;    // channel chunking
constexpr int PLANE = IH * IW;
constexpr int PH = IH + 2 * RAD, PW = IW + 2 * RAD;   // 84 x 116 padded x2
constexpr int NBCH = NWIN * 4;           // 3136 B-chunks (16B) per K-step
constexpr int NCHUNK = NBCH + 256;       // + 256 A-chunks = 3392
// K-major bf16 workspace layouts: x1k[b][ks][64][96][32], x2k[b][ks][84][116][32]
constexpr int ASTR = IH * IW * KC;       // per-ks stride in x1k (elements)
constexpr int BSTR = PH * PW * KC;       // per-ks stride in x2k
constexpr size_t X1T_ELEMS = (size_t)NB * NKS * ASTR;   // 12.58M
constexpr size_t X2P_ELEMS = (size_t)NB * NKS * BSTR;   // 19.96M

__device__ __forceinline__ unsigned short f2bf(float f) {
  unsigned u = __builtin_bit_cast(unsigned, f);
  u += 0x7fffu + ((u >> 16) & 1u);       // RNE
  return (unsigned short)(u >> 16);
}

// ---- pre-pass 1: x1 NCHW fp32 -> K-major [b][ks][i][j][32] bf16 ----
__global__ __launch_bounds__(256) void x1_to_kmajor(
    const float* __restrict__ src, unsigned short* __restrict__ dst) {
  __shared__ float lsf[32 * 97];
  const int blk = blockIdx.x;            // b*512 + i*8 + ct
  const int ct = blk & 7, i = (blk >> 3) & 63, b = blk >> 9;
  const int c0 = ct * 32, t = threadIdx.x;
  const float* sp = src + ((size_t)b * NC + c0) * PLANE + (size_t)i * IW;
#pragma unroll
  for (int k = 0; k < 12; ++k) {
    int idx = k * 256 + t;
    int c = idx / 96, j = idx - c * 96;
    lsf[c * 97 + j] = sp[(size_t)c * PLANE + j];
  }
  __syncthreads();
  unsigned short* dp = dst + (((size_t)(b * NKS + ct) * IH + i) * IW) * KC;
#pragma unroll
  for (int k = 0; k < 3; ++k) {          // 96 j x 8 cq -> contiguous 8B writes
    int o = k * 256 + t;
    int j = o >> 3, cq = o & 7;
    us4 v = {f2bf(lsf[(cq * 4 + 0) * 97 + j]), f2bf(lsf[(cq * 4 + 1) * 97 + j]),
             f2bf(lsf[(cq * 4 + 2) * 97 + j]), f2bf(lsf[(cq * 4 + 3) * 97 + j])};
    *(us4*)&dp[(size_t)j * KC + cq * 4] = v;
  }
}

// ---- pre-pass 2: x2 NCHW fp32 -> K-major halo-padded [b][ks][84][116][32], halo=0 ----
__global__ __launch_bounds__(256) void x2_to_kmajor_pad(
    const float* __restrict__ src, unsigned short* __restrict__ dst) {
  __shared__ float lsf[32 * 97];
  const int blk = blockIdx.x;            // b*(84*8) + i*8 + ct
  const int ct = blk & 7, i = (blk >> 3) % PH, b = blk / (PH * 8);
  const int c0 = ct * 32, t = threadIdx.x;
  const int isrc = i - RAD;
  const bool rowok = (unsigned)isrc < (unsigned)IH;
  if (rowok) {
    const float* sp = src + ((size_t)b * NC + c0) * PLANE + (size_t)isrc * IW;
#pragma unroll
    for (int k = 0; k < 12; ++k) {
      int idx = k * 256 + t;
      int c = idx / 96, j = idx - c * 96;
      lsf[c * 97 + j] = sp[(size_t)c * PLANE + j];
    }
  }
  __syncthreads();
  unsigned short* dp = dst + (((size_t)(b * NKS + ct) * PH + i) * PW) * KC;
#pragma unroll
  for (int k = 0; k < 4; ++k) {          // 116 j x 8 cq = 928 items
    int o = k * 256 + t;
    if (o < PW * 8) {
      int j = o >> 3, cq = o & 7;
      int jsrc = j - RAD;
      us4 v = {0, 0, 0, 0};
      if (rowok && (unsigned)jsrc < (unsigned)IW)
        v = us4{f2bf(lsf[(cq * 4 + 0) * 97 + jsrc]), f2bf(lsf[(cq * 4 + 1) * 97 + jsrc]),
                f2bf(lsf[(cq * 4 + 2) * 97 + jsrc]), f2bf(lsf[(cq * 4 + 3) * 97 + jsrc])};
      *(us4*)&dp[(size_t)j * KC + cq * 4] = v;
    }
  }
}

// ---- main: 16-wave (1024-thr) triple-buffered gload_lds pipeline ----
// Same validated R5 structure (slot swizzle, vmcnt-before-barrier), but one
// 1024-thread block per CU: acc/wave halves to 56 AGPRs -> total regs ~<128
// -> 16 waves/CU (2x occupancy vs R5's 8).
__global__ __launch_bounds__(1024, 4) void corr_pipe16(
    const unsigned short* __restrict__ x1k, const unsigned short* __restrict__ x2k,
    float* __restrict__ out) {
  __shared__ __attribute__((aligned(16))) unsigned short ls[3 * NCHUNK * 8];  // 162816 B

  const int t = threadIdx.x, lane = t & 63, wv = t >> 6;   // wv 0..15
  const int bid = blockIdx.x;
  const int b = bid & 7;                 // batch -> XCD locality
  const int tile = bid >> 3;
  const int ti = tile / 12, tj = tile - ti * 12;
  const int i0 = ti * TI, j0 = tj * TJ;
  const int mtp = wv & 1, cg = wv >> 1;  // 2 M-pairs x 8 col groups
  const int cbeg = cg * 6;               // 7 col-tiles each, overlap deduped at store
  const int qk = lane >> 4, lr = lane & 15;

  const unsigned short* x1b = x1k + (size_t)b * NKS * ASTR;
  const unsigned short* x2b = x2k + (size_t)b * NKS * BSTR;

  // per-thread ks=0 source addresses for the 4 stage slots (q = it*1024 + t)
  const unsigned short* srcp[4];
#pragma unroll
  for (int it = 0; it < 4; ++it) {
    int q = it * 1024 + t;
    if (q < NBCH) {                       // B chunk: invert slot swizzle
      int w = ((q >> 3) << 1) | (((q >> 2) ^ (q >> 4)) & 1);
      int c4 = (q & 3) ^ (w & 3);
      int wi = w / WIN, wj = w - wi * WIN;
      srcp[it] = x2b + ((size_t)(i0 + wi) * PW + (j0 + wj)) * KC + c4 * 8;
    } else {                              // A chunk: same inverse on qa
      int qa = (q - NBCH) & 255;
      int m = ((qa >> 3) << 1) | (((qa >> 2) ^ (qa >> 4)) & 1);
      int c4 = (qa & 3) ^ (m & 3);
      srcp[it] = x1b + ((size_t)(i0 + (m >> 3)) * IW + (j0 + (m & 7))) * KC + c4 * 8;
    }
  }

  f32x4 acc[2][7];
#pragma unroll
  for (int a = 0; a < 2; ++a)
#pragma unroll
    for (int cc = 0; cc < 7; ++cc) acc[a][cc] = (f32x4){0.f, 0.f, 0.f, 0.f};

  // slots 0-2: all 16 waves (3072 chunks); slot 3: waves 0-4 (320 chunks:
  // t<64 -> B tail, 64<=t<320 -> A). Per-wave issues: wv<5 -> 4, else 3.
#define STAGE(BUF, KS)                                                              \
  {                                                                                 \
    unsigned short* lb = &ls[(BUF) * NCHUNK * 8];                                   \
    _Pragma("unroll")                                                               \
    for (int it = 0; it < 3; ++it)                                                  \
      __builtin_amdgcn_global_load_lds(                                             \
          (const void*)(srcp[it] + (size_t)(KS) * BSTR),                            \
          (void*)(lb + (it * 1024 + wv * 64) * 8), 16, 0, 0);                       \
    if (wv < 5)                                                                     \
      __builtin_amdgcn_global_load_lds(                                             \
          (const void*)(srcp[3] + (size_t)(KS) * (wv == 0 ? BSTR : ASTR)),          \
          (void*)(lb + (3072 + wv * 64) * 8), 16, 0, 0);                            \
  }

#define COMPUTE(BUF)                                                                \
  {                                                                                 \
    const unsigned short* lb = &ls[(BUF) * NCHUNK * 8];                             \
    const int m0 = 32 * mtp + lr, m1 = m0 + 16;                                     \
    short8 a0 = *(const short8*)(lb + (NBCH + ((4 * m0 + qk) ^ (lr & 7))) * 8);     \
    short8 a1 = *(const short8*)(lb + (NBCH + ((4 * m1 + qk) ^ (lr & 7))) * 8);     \
    _Pragma("unroll")                                                               \
    for (int cc = 0; cc < 7; ++cc) {                                                \
      int wrow = 16 * (cbeg + cc) + lr;                                             \
      int slot = (4 * wrow + qk) ^ (lr & 7);                                        \
      short8 bf = *(const short8*)(lb + slot * 8);                                  \
      acc[0][cc] = __builtin_amdgcn_mfma_f32_16x16x32_bf16(a0, bf, acc[0][cc], 0, 0, 0); \
      acc[1][cc] = __builtin_amdgcn_mfma_f32_16x16x32_bf16(a1, bf, acc[1][cc], 0, 0, 0); \
    }                                                                               \
  }

  // prologue: stage ks=0,1
  STAGE(0, 0)
  STAGE(1, 1)

  // Validated R5 ordering: drain own stage(ks) loads BEFORE barrier (RAW);
  // barrier after COMPUTE protects the buffer restaged next iter (WAR).
  // Per-wave in-flight = 2 stages = 8 (wv<5) or 6 (wv>=5); wave-uniform branch.
#define ITER(KS, VMA, VMB)                                        \
  if ((KS) < 6) STAGE((KS + 2) % 3, KS + 2)                       \
  if (wv < 5) { asm volatile("s_waitcnt vmcnt(" #VMA ")" ::: "memory"); }  \
  else        { asm volatile("s_waitcnt vmcnt(" #VMB ")" ::: "memory"); }  \
  asm volatile("s_barrier" ::: "memory");                         \
  COMPUTE(KS % 3)                                                 \
  asm volatile("s_barrier" ::: "memory");

  ITER(0, 8, 6)
  ITER(1, 8, 6)
  ITER(2, 8, 6)
  ITER(3, 8, 6)
  ITER(4, 8, 6)
  ITER(5, 8, 6)
  ITER(6, 4, 3)
  ITER(7, 0, 0)
#undef ITER
#undef COMPUTE
#undef STAGE

  // epilogue: extract band, predicated scattered stores (validated R1..R5)
#pragma unroll
  for (int a = 0; a < 2; ++a) {
    const int mb = 16 * (2 * mtp + a) + qk * 4;
#pragma unroll
    for (int cc = 0; cc < 7; ++cc) {
      if (cg > 0 && cc == 0) continue;   // dedup overlapped col-tile
      const int n = 16 * (cbeg + cc) + lr;
      const int wi = n / WIN, wj = n - wi * WIN;
#pragma unroll
      for (int r = 0; r < 4; ++r) {
        const int m = mb + r;
        const int ii = m >> 3, jj = m & 7;
        const int pi = wi - ii, pj = wj - jj;
        if ((unsigned)pi < (unsigned)PATCH && (unsigned)pj < (unsigned)PATCH) {
          out[((((size_t)b * PATCH + pi) * PATCH + pj) * IH + (i0 + ii)) * IW + (j0 + jj)] =
              acc[a][cc][r];
        }
      }
    }
  }
}

// ---------------- fallback (R1, validated): NCHW fp32 in-kernel ----------------
constexpr int LDKF = 40;
__global__ __launch_bounds__(512, 2) void corr_mfma_fb(
    const float* __restrict__ x1, const float* __restrict__ x2, float* __restrict__ out) {
  __shared__ __attribute__((aligned(16))) unsigned short lsA[64 * LDKF];
  __shared__ __attribute__((aligned(16))) unsigned short lsB[NWIN * LDKF];
  const int t = threadIdx.x;
  const int b = blockIdx.y;
  const int ti = blockIdx.x / 12, tj = blockIdx.x % 12;
  const int i0 = ti * TI, j0 = tj * TJ;
  const int lane = t & 63, wv = t >> 6;
  const int mtp = wv >> 2, cg = wv & 3, cbeg = cg * 12;
  const int qk = lane >> 4, lr = lane & 15;
  f32x4 acc[2][13];
#pragma unroll
  for (int a = 0; a < 2; ++a)
#pragma unroll
    for (int cc = 0; cc < 13; ++cc) acc[a][cc] = (f32x4){0.f, 0.f, 0.f, 0.f};
  const int am = t & 63, ak4 = t >> 6;
  const int aii = am >> 3, ajj = am & 7;
  const float* x1p = x1 + ((size_t)b * NC + 4 * ak4) * PLANE + (size_t)(i0 + aii) * IW + (j0 + ajj);
  const float* x2b = x2 + (size_t)b * NC * PLANE;
  for (int ks = 0; ks < NKS; ++ks) {
    __syncthreads();
    {
      const float* p = x1p + (size_t)ks * KC * PLANE;
      us4 v = {f2bf(p[0]), f2bf(p[PLANE]), f2bf(p[2 * PLANE]), f2bf(p[3 * PLANE])};
      *(us4*)&lsA[am * LDKF + 4 * ak4] = v;
    }
    for (int w = t; w < NWIN; w += 512) {
      const int wi = w / WIN, wj = w - wi * WIN;
      const int gi = i0 - RAD + wi, gj = j0 - RAD + wj;
      const bool ok = ((unsigned)gi < (unsigned)IH) && ((unsigned)gj < (unsigned)IW);
      const float* p = x2b + ((size_t)(ks * KC) * IH + gi) * IW + gj;
      unsigned short* dst = &lsB[w * LDKF];
#pragma unroll
      for (int k4 = 0; k4 < 8; ++k4) {
        const float* q = p + (size_t)(4 * k4) * PLANE;
        us4 v = {f2bf(ok ? q[0] : 0.f), f2bf(ok ? q[PLANE] : 0.f),
                 f2bf(ok ? q[2 * PLANE] : 0.f), f2bf(ok ? q[3 * PLANE] : 0.f)};
        *(us4*)&dst[4 * k4] = v;
      }
    }
    __syncthreads();
    short8 a0 = *(const short8*)&lsA[(32 * mtp + lr) * LDKF + 8 * qk];
    short8 a1 = *(const short8*)&lsA[(32 * mtp + 16 + lr) * LDKF + 8 * qk];
#pragma unroll
    for (int cc = 0; cc < 13; ++cc) {
      const int wrow = 16 * (cbeg + cc) + lr;
      short8 bf = *(const short8*)&lsB[wrow * LDKF + 8 * qk];
      acc[0][cc] = __builtin_amdgcn_mfma_f32_16x16x32_bf16(a0, bf, acc[0][cc], 0, 0, 0);
      acc[1][cc] = __builtin_amdgcn_mfma_f32_16x16x32_bf16(a1, bf, acc[1][cc], 0, 0, 0);
    }
  }
#pragma unroll
  for (int a = 0; a < 2; ++a) {
    const int mb = 16 * (2 * mtp + a) + qk * 4;
#pragma unroll
    for (int cc = 0; cc < 13; ++cc) {
      if (cg > 0 && cc == 0) continue;
      const int n = 16 * (cbeg + cc) + lr;
      const int wi = n / WIN, wj = n - wi * WIN;
#pragma unroll
      for (int r = 0; r < 4; ++r) {
        const int m = mb + r;
        const int ii = m >> 3, jj = m & 7;
        const int pi = wi - ii, pj = wj - jj;
        if ((unsigned)pi < (unsigned)PATCH && (unsigned)pj < (unsigned)PATCH)
          out[((((size_t)b * PATCH + pi) * PATCH + pj) * IH + (i0 + ii)) * IW + (j0 + jj)] =
              acc[a][cc][r];
      }
    }
  }
}

extern "C" void kernel_launch(void* const* d_in, const int* in_sizes, int n_in,
                              void* d_out, int out_size, void* d_ws, size_t ws_size,
                              hipStream_t stream) {
  const float* x1 = (const float*)d_in[0];
  const float* x2 = (const float*)d_in[1];
  float* out = (float*)d_out;
  const size_t need = (X1T_ELEMS + X2P_ELEMS) * sizeof(unsigned short);  // ~65.1 MB
  if (ws_size >= need) {
    unsigned short* x1k = (unsigned short*)d_ws;
    unsigned short* x2k = x1k + X1T_ELEMS;
    x1_to_kmajor<<<NB * IH * 8, 256, 0, stream>>>(x1, x1k);
    x2_to_kmajor_pad<<<NB * PH * 8, 256, 0, stream>>>(x2, x2k);
    corr_pipe16<<<NB * 96, 1024, 0, stream>>>(x1k, x2k, out);
  } else {
    dim3 grid(96, NB);
    corr_mfma_fb<<<grid, 512, 0, stream>>>(x1, x2, out);
  }
}

// Round 7
// 95.132 us; speedup vs baseline: 1.2695x; 1.2695x over previous
//
#include <hip/hip_runtime.h>

typedef __attribute__((ext_vector_type(8))) short short8;
typedef __attribute__((ext_vector_type(4))) float f32x4;
typedef __attribute__((ext_vector_type(4))) unsigned short us4;

constexpr int NB = 8, NC = 256, IH = 64, IW = 96;
constexpr int PATCH = 21, RAD = 10;
constexpr int TI = 8, TJ = 8;            // pixel tile
constexpr int WIN = 28, NWIN = 784;      // x2 window per tile
constexpr int KC = 32, NKS = NC / KC;    // channel chunking
constexpr int PLANE = IH * IW;
constexpr int PH = IH + 2 * RAD, PW = IW + 2 * RAD;   // 84 x 116 padded x2
constexpr int NBCH = NWIN * 4;           // 3136 B-chunks (16B) per K-step
constexpr int NCHUNK = NBCH + 256;       // + 256 A-chunks = 3392
// K-major bf16 workspace layouts: x1k[b][ks][64][96][32], x2k[b][ks][84][116][32]
constexpr int ASTR = IH * IW * KC;       // per-ks stride in x1k (elements)
constexpr int BSTR = PH * PW * KC;       // per-ks stride in x2k
constexpr size_t X1T_ELEMS = (size_t)NB * NKS * ASTR;   // 12.58M
constexpr size_t X2P_ELEMS = (size_t)NB * NKS * BSTR;   // 19.96M
constexpr int GSTR = 65;                 // G-chunk m-stride (floats): diag reads bank +1

__device__ __forceinline__ unsigned short f2bf(float f) {
  unsigned u = __builtin_bit_cast(unsigned, f);
  u += 0x7fffu + ((u >> 16) & 1u);       // RNE
  return (unsigned short)(u >> 16);
}

// ---- pre-pass 1: x1 NCHW fp32 -> K-major [b][ks][i][j][32] bf16 ----
__global__ __launch_bounds__(256) void x1_to_kmajor(
    const float* __restrict__ src, unsigned short* __restrict__ dst) {
  __shared__ float lsf[32 * 97];
  const int blk = blockIdx.x;            // b*512 + i*8 + ct
  const int ct = blk & 7, i = (blk >> 3) & 63, b = blk >> 9;
  const int c0 = ct * 32, t = threadIdx.x;
  const float* sp = src + ((size_t)b * NC + c0) * PLANE + (size_t)i * IW;
#pragma unroll
  for (int k = 0; k < 12; ++k) {
    int idx = k * 256 + t;
    int c = idx / 96, j = idx - c * 96;
    lsf[c * 97 + j] = sp[(size_t)c * PLANE + j];
  }
  __syncthreads();
  unsigned short* dp = dst + (((size_t)(b * NKS + ct) * IH + i) * IW) * KC;
#pragma unroll
  for (int k = 0; k < 3; ++k) {          // 96 j x 8 cq -> contiguous 8B writes
    int o = k * 256 + t;
    int j = o >> 3, cq = o & 7;
    us4 v = {f2bf(lsf[(cq * 4 + 0) * 97 + j]), f2bf(lsf[(cq * 4 + 1) * 97 + j]),
             f2bf(lsf[(cq * 4 + 2) * 97 + j]), f2bf(lsf[(cq * 4 + 3) * 97 + j])};
    *(us4*)&dp[(size_t)j * KC + cq * 4] = v;
  }
}

// ---- pre-pass 2: x2 NCHW fp32 -> K-major halo-padded [b][ks][84][116][32], halo=0 ----
__global__ __launch_bounds__(256) void x2_to_kmajor_pad(
    const float* __restrict__ src, unsigned short* __restrict__ dst) {
  __shared__ float lsf[32 * 97];
  const int blk = blockIdx.x;            // b*(84*8) + i*8 + ct
  const int ct = blk & 7, i = (blk >> 3) % PH, b = blk / (PH * 8);
  const int c0 = ct * 32, t = threadIdx.x;
  const int isrc = i - RAD;
  const bool rowok = (unsigned)isrc < (unsigned)IH;
  if (rowok) {
    const float* sp = src + ((size_t)b * NC + c0) * PLANE + (size_t)isrc * IW;
#pragma unroll
    for (int k = 0; k < 12; ++k) {
      int idx = k * 256 + t;
      int c = idx / 96, j = idx - c * 96;
      lsf[c * 97 + j] = sp[(size_t)c * PLANE + j];
    }
  }
  __syncthreads();
  unsigned short* dp = dst + (((size_t)(b * NKS + ct) * PH + i) * PW) * KC;
#pragma unroll
  for (int k = 0; k < 4; ++k) {          // 116 j x 8 cq = 928 items
    int o = k * 256 + t;
    if (o < PW * 8) {
      int j = o >> 3, cq = o & 7;
      int jsrc = j - RAD;
      us4 v = {0, 0, 0, 0};
      if (rowok && (unsigned)jsrc < (unsigned)IW)
        v = us4{f2bf(lsf[(cq * 4 + 0) * 97 + jsrc]), f2bf(lsf[(cq * 4 + 1) * 97 + jsrc]),
                f2bf(lsf[(cq * 4 + 2) * 97 + jsrc]), f2bf(lsf[(cq * 4 + 3) * 97 + jsrc])};
      *(us4*)&dp[(size_t)j * KC + cq * 4] = v;
    }
  }
}

// ---- main: 16-wave triple-buffered gload_lds pipeline + coalesced epilogue ----
__global__ __launch_bounds__(1024, 4) void corr_pipe16(
    const unsigned short* __restrict__ x1k, const unsigned short* __restrict__ x2k,
    float* __restrict__ out) {
  __shared__ __attribute__((aligned(16))) unsigned short ls[3 * NCHUNK * 8];  // 162816 B

  const int t = threadIdx.x, lane = t & 63, wv = t >> 6;   // wv 0..15
  const int bid = blockIdx.x;
  const int b = bid & 7;                 // batch -> XCD locality
  const int tile = bid >> 3;
  const int ti = tile / 12, tj = tile - ti * 12;
  const int i0 = ti * TI, j0 = tj * TJ;
  const int mtp = wv & 1, cg = wv >> 1;  // 2 M-pairs x 8 col groups
  const int cbeg = cg * 6;               // 7 col-tiles each (overlap: duplicate G writes, benign)
  const int qk = lane >> 4, lr = lane & 15;

  const unsigned short* x1b = x1k + (size_t)b * NKS * ASTR;
  const unsigned short* x2b = x2k + (size_t)b * NKS * BSTR;

  // per-thread ks=0 source addresses for the 4 stage slots (q = it*1024 + t)
  const unsigned short* srcp[4];
#pragma unroll
  for (int it = 0; it < 4; ++it) {
    int q = it * 1024 + t;
    if (q < NBCH) {                       // B chunk: invert slot swizzle
      int w = ((q >> 3) << 1) | (((q >> 2) ^ (q >> 4)) & 1);
      int c4 = (q & 3) ^ (w & 3);
      int wi = w / WIN, wj = w - wi * WIN;
      srcp[it] = x2b + ((size_t)(i0 + wi) * PW + (j0 + wj)) * KC + c4 * 8;
    } else {                              // A chunk: same inverse on qa
      int qa = (q - NBCH) & 255;
      int m = ((qa >> 3) << 1) | (((qa >> 2) ^ (qa >> 4)) & 1);
      int c4 = (qa & 3) ^ (m & 3);
      srcp[it] = x1b + ((size_t)(i0 + (m >> 3)) * IW + (j0 + (m & 7))) * KC + c4 * 8;
    }
  }

  f32x4 acc[2][7];
#pragma unroll
  for (int a = 0; a < 2; ++a)
#pragma unroll
    for (int cc = 0; cc < 7; ++cc) acc[a][cc] = (f32x4){0.f, 0.f, 0.f, 0.f};

#define STAGE(BUF, KS)                                                              \
  {                                                                                 \
    unsigned short* lb = &ls[(BUF) * NCHUNK * 8];                                   \
    _Pragma("unroll")                                                               \
    for (int it = 0; it < 3; ++it)                                                  \
      __builtin_amdgcn_global_load_lds(                                             \
          (const void*)(srcp[it] + (size_t)(KS) * BSTR),                            \
          (void*)(lb + (it * 1024 + wv * 64) * 8), 16, 0, 0);                       \
    if (wv < 5)                                                                     \
      __builtin_amdgcn_global_load_lds(                                             \
          (const void*)(srcp[3] + (size_t)(KS) * (wv == 0 ? BSTR : ASTR)),          \
          (void*)(lb + (3072 + wv * 64) * 8), 16, 0, 0);                            \
  }

#define COMPUTE(BUF)                                                                \
  {                                                                                 \
    const unsigned short* lb = &ls[(BUF) * NCHUNK * 8];                             \
    const int m0 = 32 * mtp + lr, m1 = m0 + 16;                                     \
    short8 a0 = *(const short8*)(lb + (NBCH + ((4 * m0 + qk) ^ (lr & 7))) * 8);     \
    short8 a1 = *(const short8*)(lb + (NBCH + ((4 * m1 + qk) ^ (lr & 7))) * 8);     \
    _Pragma("unroll")                                                               \
    for (int cc = 0; cc < 7; ++cc) {                                                \
      int wrow = 16 * (cbeg + cc) + lr;                                             \
      int slot = (4 * wrow + qk) ^ (lr & 7);                                        \
      short8 bf = *(const short8*)(lb + slot * 8);                                  \
      acc[0][cc] = __builtin_amdgcn_mfma_f32_16x16x32_bf16(a0, bf, acc[0][cc], 0, 0, 0); \
      acc[1][cc] = __builtin_amdgcn_mfma_f32_16x16x32_bf16(a1, bf, acc[1][cc], 0, 0, 0); \
    }                                                                               \
  }

  // prologue: stage ks=0,1
  STAGE(0, 0)
  STAGE(1, 1)

  // Validated R5/R6 ordering: drain own stage(ks) loads BEFORE barrier (RAW);
  // barrier after COMPUTE protects the buffer restaged next iter (WAR).
#define ITER(KS, VMA, VMB)                                        \
  if ((KS) < 6) STAGE((KS + 2) % 3, KS + 2)                       \
  if (wv < 5) { asm volatile("s_waitcnt vmcnt(" #VMA ")" ::: "memory"); }  \
  else        { asm volatile("s_waitcnt vmcnt(" #VMB ")" ::: "memory"); }  \
  asm volatile("s_barrier" ::: "memory");                         \
  COMPUTE(KS % 3)                                                 \
  asm volatile("s_barrier" ::: "memory");

  ITER(0, 8, 6)
  ITER(1, 8, 6)
  ITER(2, 8, 6)
  ITER(3, 8, 6)
  ITER(4, 8, 6)
  ITER(5, 8, 6)
  ITER(6, 4, 3)
  ITER(7, 0, 0)
#undef ITER
#undef COMPUTE
#undef STAGE

  // ---- epilogue: LDS diagonal transpose -> coalesced 32B row-segment stores ----
  // out(pi,pj,ii,jj) = G[n][m], n = 28*(pi+ii) + pj + jj, m = 8*ii + jj: the
  // j-contiguous output run is a DIAGONAL of G. Stage G chunk [n][m] in LDS
  // (reusing staging buffer), gather diagonals, store 8 floats per segment.
  // Chunk 0: n<400 (cc 0..24) serves wi<=13; chunk 1: n>=384 (cc 24..48), wi>=14.
  float* gf = (float*)ls;
#pragma unroll
  for (int ch = 0; ch < 2; ++ch) {
    __syncthreads();                     // full drain: staging reads/writes done
    const int n0 = ch ? 384 : 0;
#pragma unroll
    for (int a = 0; a < 2; ++a)
#pragma unroll
      for (int cc = 0; cc < 7; ++cc) {
        int ccg = cbeg + cc;
        if (ch ? (ccg >= 24) : (ccg <= 24)) {
          int nl = 16 * ccg + lr - n0;
          int mb = 16 * (2 * mtp + a) + 4 * qk;
          float* gp = &gf[nl * GSTR + mb];
          gp[0] = acc[a][cc][0]; gp[1] = acc[a][cc][1];
          gp[2] = acc[a][cc][2]; gp[3] = acc[a][cc][3];
        }
      }
    __syncthreads();
    // 1764 segments per chunk: s = pidx*21 + pj; pidx enumerates (ii,pi) pairs
    // ch0: ii-group k has 14-k pi's (pi=rem); ch1: 7+k pi's (pi=14-k+rem).
    for (int s = t; s < 1764; s += 1024) {
      int pidx = s / 21, pj = s - pidx * 21;
      int ii = 0, rem = pidx, stop = 0;
#pragma unroll
      for (int k = 0; k < 7; ++k) {
        int cnt = ch ? (7 + k) : (14 - k);
        int go = (!stop) && (rem >= cnt);
        rem -= go ? cnt : 0;
        ii += go;
        stop |= !go;
      }
      int pi = ch ? (14 - ii + rem) : rem;
      int nl = 28 * (pi + ii) + pj - n0;
      int ms = 8 * ii;
      float g[8];
#pragma unroll
      for (int e = 0; e < 8; ++e) g[e] = gf[(nl + e) * GSTR + ms + e];
      float* op = out + ((((size_t)b * PATCH + pi) * PATCH + pj) * IH + (i0 + ii)) * IW + j0;
      f32x4 v0 = {g[0], g[1], g[2], g[3]};
      f32x4 v1 = {g[4], g[5], g[6], g[7]};
      *(f32x4*)op = v0;
      *(f32x4*)(op + 4) = v1;
    }
  }
}

// ---------------- fallback (R1, validated): NCHW fp32 in-kernel ----------------
constexpr int LDKF = 40;
__global__ __launch_bounds__(512, 2) void corr_mfma_fb(
    const float* __restrict__ x1, const float* __restrict__ x2, float* __restrict__ out) {
  __shared__ __attribute__((aligned(16))) unsigned short lsA[64 * LDKF];
  __shared__ __attribute__((aligned(16))) unsigned short lsB[NWIN * LDKF];
  const int t = threadIdx.x;
  const int b = blockIdx.y;
  const int ti = blockIdx.x / 12, tj = blockIdx.x % 12;
  const int i0 = ti * TI, j0 = tj * TJ;
  const int lane = t & 63, wv = t >> 6;
  const int mtp = wv >> 2, cg = wv & 3, cbeg = cg * 12;
  const int qk = lane >> 4, lr = lane & 15;
  f32x4 acc[2][13];
#pragma unroll
  for (int a = 0; a < 2; ++a)
#pragma unroll
    for (int cc = 0; cc < 13; ++cc) acc[a][cc] = (f32x4){0.f, 0.f, 0.f, 0.f};
  const int am = t & 63, ak4 = t >> 6;
  const int aii = am >> 3, ajj = am & 7;
  const float* x1p = x1 + ((size_t)b * NC + 4 * ak4) * PLANE + (size_t)(i0 + aii) * IW + (j0 + ajj);
  const float* x2b = x2 + (size_t)b * NC * PLANE;
  for (int ks = 0; ks < NKS; ++ks) {
    __syncthreads();
    {
      const float* p = x1p + (size_t)ks * KC * PLANE;
      us4 v = {f2bf(p[0]), f2bf(p[PLANE]), f2bf(p[2 * PLANE]), f2bf(p[3 * PLANE])};
      *(us4*)&lsA[am * LDKF + 4 * ak4] = v;
    }
    for (int w = t; w < NWIN; w += 512) {
      const int wi = w / WIN, wj = w - wi * WIN;
      const int gi = i0 - RAD + wi, gj = j0 - RAD + wj;
      const bool ok = ((unsigned)gi < (unsigned)IH) && ((unsigned)gj < (unsigned)IW);
      const float* p = x2b + ((size_t)(ks * KC) * IH + gi) * IW + gj;
      unsigned short* dst = &lsB[w * LDKF];
#pragma unroll
      for (int k4 = 0; k4 < 8; ++k4) {
        const float* q = p + (size_t)(4 * k4) * PLANE;
        us4 v = {f2bf(ok ? q[0] : 0.f), f2bf(ok ? q[PLANE] : 0.f),
                 f2bf(ok ? q[2 * PLANE] : 0.f), f2bf(ok ? q[3 * PLANE] : 0.f)};
        *(us4*)&dst[4 * k4] = v;
      }
    }
    __syncthreads();
    short8 a0 = *(const short8*)&lsA[(32 * mtp + lr) * LDKF + 8 * qk];
    short8 a1 = *(const short8*)&lsA[(32 * mtp + 16 + lr) * LDKF + 8 * qk];
#pragma unroll
    for (int cc = 0; cc < 13; ++cc) {
      const int wrow = 16 * (cbeg + cc) + lr;
      short8 bf = *(const short8*)&lsB[wrow * LDKF + 8 * qk];
      acc[0][cc] = __builtin_amdgcn_mfma_f32_16x16x32_bf16(a0, bf, acc[0][cc], 0, 0, 0);
      acc[1][cc] = __builtin_amdgcn_mfma_f32_16x16x32_bf16(a1, bf, acc[1][cc], 0, 0, 0);
    }
  }
#pragma unroll
  for (int a = 0; a < 2; ++a) {
    const int mb = 16 * (2 * mtp + a) + qk * 4;
#pragma unroll
    for (int cc = 0; cc < 13; ++cc) {
      if (cg > 0 && cc == 0) continue;
      const int n = 16 * (cbeg + cc) + lr;
      const int wi = n / WIN, wj = n - wi * WIN;
#pragma unroll
      for (int r = 0; r < 4; ++r) {
        const int m = mb + r;
        const int ii = m >> 3, jj = m & 7;
        const int pi = wi - ii, pj = wj - jj;
        if ((unsigned)pi < (unsigned)PATCH && (unsigned)pj < (unsigned)PATCH)
          out[((((size_t)b * PATCH + pi) * PATCH + pj) * IH + (i0 + ii)) * IW + (j0 + jj)] =
              acc[a][cc][r];
      }
    }
  }
}

extern "C" void kernel_launch(void* const* d_in, const int* in_sizes, int n_in,
                              void* d_out, int out_size, void* d_ws, size_t ws_size,
                              hipStream_t stream) {
  const float* x1 = (const float*)d_in[0];
  const float* x2 = (const float*)d_in[1];
  float* out = (float*)d_out;
  const size_t need = (X1T_ELEMS + X2P_ELEMS) * sizeof(unsigned short);  // ~65.1 MB
  if (ws_size >= need) {
    unsigned short* x1k = (unsigned short*)d_ws;
    unsigned short* x2k = x1k + X1T_ELEMS;
    x1_to_kmajor<<<NB * IH * 8, 256, 0, stream>>>(x1, x1k);
    x2_to_kmajor_pad<<<NB * PH * 8, 256, 0, stream>>>(x2, x2k);
    corr_pipe16<<<NB * 96, 1024, 0, stream>>>(x1k, x2k, out);
  } else {
    dim3 grid(96, NB);
    corr_mfma_fb<<<grid, 512, 0, stream>>>(x1, x2, out);
  }
}

// Round 8
// 86.132 us; speedup vs baseline: 1.4021x; 1.1045x over previous
//
#include <hip/hip_runtime.h>

typedef __attribute__((ext_vector_type(8))) short short8;
typedef __attribute__((ext_vector_type(4))) float f32x4;
typedef __attribute__((ext_vector_type(4))) unsigned short us4;

constexpr int NB = 8, NC = 256, IH = 64, IW = 96;
constexpr int PATCH = 21, RAD = 10;
constexpr int TI = 8, TJ = 8;            // pixel tile
constexpr int WIN = 28, NWIN = 784;      // x2 window per tile
constexpr int KC = 32, NKS = NC / KC;    // channel chunking
constexpr int PLANE = IH * IW;
constexpr int PH = IH + 2 * RAD, PW = IW + 2 * RAD;   // 84 x 116 padded x2
constexpr int NBCH = NWIN * 4;           // 3136 B-chunks (16B) per K-step
constexpr int NCHUNK = NBCH + 256;       // + 256 A-chunks = 3392
// K-major bf16 workspace layouts: x1k[b][ks][64][96][32], x2k[b][ks][84][116][32]
constexpr int ASTR = IH * IW * KC;       // per-ks stride in x1k (elements)
constexpr int BSTR = PH * PW * KC;       // per-ks stride in x2k
constexpr size_t X1T_ELEMS = (size_t)NB * NKS * ASTR;   // 12.58M
constexpr size_t X2P_ELEMS = (size_t)NB * NKS * BSTR;   // 19.96M
constexpr int GSTR = 65;                 // G-chunk m-stride (floats): diag reads bank +1

__device__ __forceinline__ unsigned short f2bf(float f) {
  unsigned u = __builtin_bit_cast(unsigned, f);
  u += 0x7fffu + ((u >> 16) & 1u);       // RNE
  return (unsigned short)(u >> 16);
}

// ---- pre-pass 1: x1 NCHW fp32 -> K-major [b][ks][i][j][32] bf16 ----
__global__ __launch_bounds__(256) void x1_to_kmajor(
    const float* __restrict__ src, unsigned short* __restrict__ dst) {
  __shared__ float lsf[32 * 97];
  const int blk = blockIdx.x;            // b*512 + i*8 + ct
  const int ct = blk & 7, i = (blk >> 3) & 63, b = blk >> 9;
  const int c0 = ct * 32, t = threadIdx.x;
  const float* sp = src + ((size_t)b * NC + c0) * PLANE + (size_t)i * IW;
#pragma unroll
  for (int k = 0; k < 12; ++k) {
    int idx = k * 256 + t;
    int c = idx / 96, j = idx - c * 96;
    lsf[c * 97 + j] = sp[(size_t)c * PLANE + j];
  }
  __syncthreads();
  unsigned short* dp = dst + (((size_t)(b * NKS + ct) * IH + i) * IW) * KC;
#pragma unroll
  for (int k = 0; k < 3; ++k) {          // 96 j x 8 cq -> contiguous 8B writes
    int o = k * 256 + t;
    int j = o >> 3, cq = o & 7;
    us4 v = {f2bf(lsf[(cq * 4 + 0) * 97 + j]), f2bf(lsf[(cq * 4 + 1) * 97 + j]),
             f2bf(lsf[(cq * 4 + 2) * 97 + j]), f2bf(lsf[(cq * 4 + 3) * 97 + j])};
    *(us4*)&dp[(size_t)j * KC + cq * 4] = v;
  }
}

// ---- pre-pass 2: x2 NCHW fp32 -> K-major halo-padded [b][ks][84][116][32], halo=0 ----
__global__ __launch_bounds__(256) void x2_to_kmajor_pad(
    const float* __restrict__ src, unsigned short* __restrict__ dst) {
  __shared__ float lsf[32 * 97];
  const int blk = blockIdx.x;            // b*(84*8) + i*8 + ct
  const int ct = blk & 7, i = (blk >> 3) % PH, b = blk / (PH * 8);
  const int c0 = ct * 32, t = threadIdx.x;
  const int isrc = i - RAD;
  const bool rowok = (unsigned)isrc < (unsigned)IH;
  if (rowok) {
    const float* sp = src + ((size_t)b * NC + c0) * PLANE + (size_t)isrc * IW;
#pragma unroll
    for (int k = 0; k < 12; ++k) {
      int idx = k * 256 + t;
      int c = idx / 96, j = idx - c * 96;
      lsf[c * 97 + j] = sp[(size_t)c * PLANE + j];
    }
  }
  __syncthreads();
  unsigned short* dp = dst + (((size_t)(b * NKS + ct) * PH + i) * PW) * KC;
#pragma unroll
  for (int k = 0; k < 4; ++k) {          // 116 j x 8 cq = 928 items
    int o = k * 256 + t;
    if (o < PW * 8) {
      int j = o >> 3, cq = o & 7;
      int jsrc = j - RAD;
      us4 v = {0, 0, 0, 0};
      if (rowok && (unsigned)jsrc < (unsigned)IW)
        v = us4{f2bf(lsf[(cq * 4 + 0) * 97 + jsrc]), f2bf(lsf[(cq * 4 + 1) * 97 + jsrc]),
                f2bf(lsf[(cq * 4 + 2) * 97 + jsrc]), f2bf(lsf[(cq * 4 + 3) * 97 + jsrc])};
      *(us4*)&dp[(size_t)j * KC + cq * 4] = v;
    }
  }
}

// ---- main: 8-wave triple-buffered gload_lds pipeline, full-M waves ----
// Each wave computes ALL 4 M-tiles for its 7 col-tiles: every staged B
// fragment is ds_read ONCE (R7 read it twice via the mtp pair) -> K-loop
// LDS read volume -39%.
__global__ __launch_bounds__(512, 2) void corr_pipe8(
    const unsigned short* __restrict__ x1k, const unsigned short* __restrict__ x2k,
    float* __restrict__ out) {
  __shared__ __attribute__((aligned(16))) unsigned short ls[3 * NCHUNK * 8];  // 162816 B

  const int t = threadIdx.x, lane = t & 63, wv = t >> 6;   // wv 0..7
  const int bid = blockIdx.x;
  const int b = bid & 7;                 // batch -> XCD locality
  const int tile = bid >> 3;
  const int ti = tile / 12, tj = tile - ti * 12;
  const int i0 = ti * TI, j0 = tj * TJ;
  const int cbeg = 6 * wv;               // 7 col-tiles/wave; overlap tiles bitwise-identical
  const int qk = lane >> 4, lr = lane & 15;

  const unsigned short* x1b = x1k + (size_t)b * NKS * ASTR;
  const unsigned short* x2b = x2k + (size_t)b * NKS * BSTR;

  // per-thread ks=0 source addresses for the 7 stage slots (q = it*512 + t)
  // (byte-identical to validated R5 enumeration)
  const unsigned short* srcp[7];
#pragma unroll
  for (int it = 0; it < 7; ++it) {
    int q = it * 512 + t;
    if (q < NBCH) {                       // B chunk: invert slot swizzle
      int w = ((q >> 3) << 1) | (((q >> 2) ^ (q >> 4)) & 1);
      int c4 = (q & 3) ^ (w & 3);
      int wi = w / WIN, wj = w - wi * WIN;
      srcp[it] = x2b + ((size_t)(i0 + wi) * PW + (j0 + wj)) * KC + c4 * 8;
    } else {                              // A chunk: same inverse on qa
      int qa = (q - NBCH) & 255;
      int m = ((qa >> 3) << 1) | (((qa >> 2) ^ (qa >> 4)) & 1);
      int c4 = (qa & 3) ^ (m & 3);
      srcp[it] = x1b + ((size_t)(i0 + (m >> 3)) * IW + (j0 + (m & 7))) * KC + c4 * 8;
    }
  }

  f32x4 acc[4][7];
#pragma unroll
  for (int a = 0; a < 4; ++a)
#pragma unroll
    for (int cc = 0; cc < 7; ++cc) acc[a][cc] = (f32x4){0.f, 0.f, 0.f, 0.f};

#define STAGE(BUF, KS)                                                              \
  {                                                                                 \
    unsigned short* lb = &ls[(BUF) * NCHUNK * 8];                                   \
    _Pragma("unroll")                                                               \
    for (int it = 0; it < 6; ++it)                                                  \
      __builtin_amdgcn_global_load_lds(                                             \
          (const void*)(srcp[it] + (size_t)(KS) * BSTR),                            \
          (void*)(lb + (it * 512 + wv * 64) * 8), 16, 0, 0);                        \
    if (wv < 5)                                                                     \
      __builtin_amdgcn_global_load_lds(                                             \
          (const void*)(srcp[6] + (size_t)(KS) * (wv == 0 ? BSTR : ASTR)),          \
          (void*)(lb + (3072 + wv * 64) * 8), 16, 0, 0);                            \
  }

#define COMPUTE(BUF)                                                                \
  {                                                                                 \
    const unsigned short* lb = &ls[(BUF) * NCHUNK * 8];                             \
    short8 af0 = *(const short8*)(lb + (NBCH + ((4 * (lr) + qk) ^ (lr & 7))) * 8);        \
    short8 af1 = *(const short8*)(lb + (NBCH + ((4 * (16 + lr) + qk) ^ (lr & 7))) * 8);   \
    short8 af2 = *(const short8*)(lb + (NBCH + ((4 * (32 + lr) + qk) ^ (lr & 7))) * 8);   \
    short8 af3 = *(const short8*)(lb + (NBCH + ((4 * (48 + lr) + qk) ^ (lr & 7))) * 8);   \
    _Pragma("unroll")                                                               \
    for (int cc = 0; cc < 7; ++cc) {                                                \
      int wrow = 16 * (cbeg + cc) + lr;                                             \
      int slot = (4 * wrow + qk) ^ (lr & 7);                                        \
      short8 bf = *(const short8*)(lb + slot * 8);                                  \
      acc[0][cc] = __builtin_amdgcn_mfma_f32_16x16x32_bf16(af0, bf, acc[0][cc], 0, 0, 0); \
      acc[1][cc] = __builtin_amdgcn_mfma_f32_16x16x32_bf16(af1, bf, acc[1][cc], 0, 0, 0); \
      acc[2][cc] = __builtin_amdgcn_mfma_f32_16x16x32_bf16(af2, bf, acc[2][cc], 0, 0, 0); \
      acc[3][cc] = __builtin_amdgcn_mfma_f32_16x16x32_bf16(af3, bf, acc[3][cc], 0, 0, 0); \
    }                                                                               \
  }

  // prologue: stage ks=0,1
  STAGE(0, 0)
  STAGE(1, 1)

  // Validated R5 ordering: drain own stage(ks) loads BEFORE barrier (RAW);
  // barrier after COMPUTE protects the buffer restaged next iter (WAR).
#define ITER(KS, VM)                                           \
  if ((KS) < 6) STAGE((KS + 2) % 3, KS + 2)                    \
  asm volatile("s_waitcnt vmcnt(" #VM ")" ::: "memory");       \
  asm volatile("s_barrier" ::: "memory");                      \
  COMPUTE(KS % 3)                                              \
  asm volatile("s_barrier" ::: "memory");

  ITER(0, 12)
  ITER(1, 12)
  ITER(2, 12)
  ITER(3, 12)
  ITER(4, 12)
  ITER(5, 12)
  ITER(6, 6)
  ITER(7, 0)
#undef ITER
#undef COMPUTE
#undef STAGE

  // ---- epilogue: LDS diagonal transpose -> coalesced 32B row-segment stores ----
  // (validated R7 structure; 512 threads, acc[4][7], m = 16a + 4qk + r)
  float* gf = (float*)ls;
#pragma unroll
  for (int ch = 0; ch < 2; ++ch) {
    __syncthreads();                     // full drain: staging reads/writes done
    const int n0 = ch ? 384 : 0;
#pragma unroll
    for (int a = 0; a < 4; ++a)
#pragma unroll
      for (int cc = 0; cc < 7; ++cc) {
        int ccg = cbeg + cc;
        if (ch ? (ccg >= 24) : (ccg <= 24)) {
          int nl = 16 * ccg + lr - n0;
          int mb = 16 * a + 4 * qk;
          float* gp = &gf[nl * GSTR + mb];
          gp[0] = acc[a][cc][0]; gp[1] = acc[a][cc][1];
          gp[2] = acc[a][cc][2]; gp[3] = acc[a][cc][3];
        }
      }
    __syncthreads();
    // 1764 segments per chunk: s = pidx*21 + pj; pidx enumerates (ii,pi) pairs
    // ch0: ii-group k has 14-k pi's (pi=rem); ch1: 7+k pi's (pi=14-k+rem).
    for (int s = t; s < 1764; s += 512) {
      int pidx = s / 21, pj = s - pidx * 21;
      int ii = 0, rem = pidx, stop = 0;
#pragma unroll
      for (int k = 0; k < 7; ++k) {
        int cnt = ch ? (7 + k) : (14 - k);
        int go = (!stop) && (rem >= cnt);
        rem -= go ? cnt : 0;
        ii += go;
        stop |= !go;
      }
      int pi = ch ? (14 - ii + rem) : rem;
      int nl = 28 * (pi + ii) + pj - n0;
      int ms = 8 * ii;
      float g[8];
#pragma unroll
      for (int e = 0; e < 8; ++e) g[e] = gf[(nl + e) * GSTR + ms + e];
      float* op = out + ((((size_t)b * PATCH + pi) * PATCH + pj) * IH + (i0 + ii)) * IW + j0;
      f32x4 v0 = {g[0], g[1], g[2], g[3]};
      f32x4 v1 = {g[4], g[5], g[6], g[7]};
      *(f32x4*)op = v0;
      *(f32x4*)(op + 4) = v1;
    }
  }
}

// ---------------- fallback (R1, validated): NCHW fp32 in-kernel ----------------
constexpr int LDKF = 40;
__global__ __launch_bounds__(512, 2) void corr_mfma_fb(
    const float* __restrict__ x1, const float* __restrict__ x2, float* __restrict__ out) {
  __shared__ __attribute__((aligned(16))) unsigned short lsA[64 * LDKF];
  __shared__ __attribute__((aligned(16))) unsigned short lsB[NWIN * LDKF];
  const int t = threadIdx.x;
  const int b = blockIdx.y;
  const int ti = blockIdx.x / 12, tj = blockIdx.x % 12;
  const int i0 = ti * TI, j0 = tj * TJ;
  const int lane = t & 63, wv = t >> 6;
  const int mtp = wv >> 2, cg = wv & 3, cbeg = cg * 12;
  const int qk = lane >> 4, lr = lane & 15;
  f32x4 acc[2][13];
#pragma unroll
  for (int a = 0; a < 2; ++a)
#pragma unroll
    for (int cc = 0; cc < 13; ++cc) acc[a][cc] = (f32x4){0.f, 0.f, 0.f, 0.f};
  const int am = t & 63, ak4 = t >> 6;
  const int aii = am >> 3, ajj = am & 7;
  const float* x1p = x1 + ((size_t)b * NC + 4 * ak4) * PLANE + (size_t)(i0 + aii) * IW + (j0 + ajj);
  const float* x2b = x2 + (size_t)b * NC * PLANE;
  for (int ks = 0; ks < NKS; ++ks) {
    __syncthreads();
    {
      const float* p = x1p + (size_t)ks * KC * PLANE;
      us4 v = {f2bf(p[0]), f2bf(p[PLANE]), f2bf(p[2 * PLANE]), f2bf(p[3 * PLANE])};
      *(us4*)&lsA[am * LDKF + 4 * ak4] = v;
    }
    for (int w = t; w < NWIN; w += 512) {
      const int wi = w / WIN, wj = w - wi * WIN;
      const int gi = i0 - RAD + wi, gj = j0 - RAD + wj;
      const bool ok = ((unsigned)gi < (unsigned)IH) && ((unsigned)gj < (unsigned)IW);
      const float* p = x2b + ((size_t)(ks * KC) * IH + gi) * IW + gj;
      unsigned short* dst = &lsB[w * LDKF];
#pragma unroll
      for (int k4 = 0; k4 < 8; ++k4) {
        const float* q = p + (size_t)(4 * k4) * PLANE;
        us4 v = {f2bf(ok ? q[0] : 0.f), f2bf(ok ? q[PLANE] : 0.f),
                 f2bf(ok ? q[2 * PLANE] : 0.f), f2bf(ok ? q[3 * PLANE] : 0.f)};
        *(us4*)&dst[4 * k4] = v;
      }
    }
    __syncthreads();
    short8 a0 = *(const short8*)&lsA[(32 * mtp + lr) * LDKF + 8 * qk];
    short8 a1 = *(const short8*)&lsA[(32 * mtp + 16 + lr) * LDKF + 8 * qk];
#pragma unroll
    for (int cc = 0; cc < 13; ++cc) {
      const int wrow = 16 * (cbeg + cc) + lr;
      short8 bf = *(const short8*)&lsB[wrow * LDKF + 8 * qk];
      acc[0][cc] = __builtin_amdgcn_mfma_f32_16x16x32_bf16(a0, bf, acc[0][cc], 0, 0, 0);
      acc[1][cc] = __builtin_amdgcn_mfma_f32_16x16x32_bf16(a1, bf, acc[1][cc], 0, 0, 0);
    }
  }
#pragma unroll
  for (int a = 0; a < 2; ++a) {
    const int mb = 16 * (2 * mtp + a) + qk * 4;
#pragma unroll
    for (int cc = 0; cc < 13; ++cc) {
      if (cg > 0 && cc == 0) continue;
      const int n = 16 * (cbeg + cc) + lr;
      const int wi = n / WIN, wj = n - wi * WIN;
#pragma unroll
      for (int r = 0; r < 4; ++r) {
        const int m = mb + r;
        const int ii = m >> 3, jj = m & 7;
        const int pi = wi - ii, pj = wj - jj;
        if ((unsigned)pi < (unsigned)PATCH && (unsigned)pj < (unsigned)PATCH)
          out[((((size_t)b * PATCH + pi) * PATCH + pj) * IH + (i0 + ii)) * IW + (j0 + jj)] =
              acc[a][cc][r];
      }
    }
  }
}

extern "C" void kernel_launch(void* const* d_in, const int* in_sizes, int n_in,
                              void* d_out, int out_size, void* d_ws, size_t ws_size,
                              hipStream_t stream) {
  const float* x1 = (const float*)d_in[0];
  const float* x2 = (const float*)d_in[1];
  float* out = (float*)d_out;
  const size_t need = (X1T_ELEMS + X2P_ELEMS) * sizeof(unsigned short);  // ~65.1 MB
  if (ws_size >= need) {
    unsigned short* x1k = (unsigned short*)d_ws;
    unsigned short* x2k = x1k + X1T_ELEMS;
    x1_to_kmajor<<<NB * IH * 8, 256, 0, stream>>>(x1, x1k);
    x2_to_kmajor_pad<<<NB * PH * 8, 256, 0, stream>>>(x2, x2k);
    corr_pipe8<<<NB * 96, 512, 0, stream>>>(x1k, x2k, out);
  } else {
    dim3 grid(96, NB);
    corr_mfma_fb<<<grid, 512, 0, stream>>>(x1, x2, out);
  }
}